// Round 10
// baseline (194.956 us; speedup 1.0000x reference)
//
#include <hip/hip_runtime.h>

typedef __attribute__((ext_vector_type(8))) short short8;
typedef __attribute__((ext_vector_type(4))) float f32x4;
typedef __attribute__((ext_vector_type(4))) unsigned short u16x4;

#define B_   4
#define C_   2048
#define HW_  196
#define P_   784      // B_*HW_
#define NCLS 80
#define WD   300
#define ID   1024
#define LG_N 62720    // NCLS * P_

// workspace layout (float offsets)
#define WP_OFF    0          // word_p [80][1024]
#define VPART_OFF 81920      // vpart [16][1024]
#define LG_OFF    98304      // logits [80][784]  (n-major)
#define ABF_BYTE  644096     // Abf [784][2048] bf16
#define WBF_BYTE  3855360    // Wbf [1024][2048] bf16

__device__ __forceinline__ unsigned short f2bf(float x) {
    unsigned u = __float_as_uint(x);
    return (unsigned short)((u + 0x7FFFu + ((u >> 16) & 1u)) >> 16);  // RNE
}

// ---- K_prep: fused independent preprocessing via block-range dispatch ----
// [0,320) word_p | [320,832) cvtW | [832,960) cvtA | [960,1024) vpart | [1024,1086) zero lg
__global__ __launch_bounds__(256) void k_prep(const float* __restrict__ img,
                                              const float* __restrict__ wf,
                                              const float* __restrict__ fc1w,
                                              const float* __restrict__ fc2w,
                                              const float* __restrict__ fc3w,
                                              const float* __restrict__ fc4w,
                                              unsigned short* __restrict__ abf,
                                              unsigned short* __restrict__ wbf,
                                              float* __restrict__ wp,
                                              float* __restrict__ vpart,
                                              float* __restrict__ lg) {
    __shared__ unsigned short tile[HW_][68];
    int bid = blockIdx.x, t = threadIdx.x;
    if (bid < 320) {                       // ---- word_p ----
        int idx = bid * 256 + t;
        int n = idx >> 10, d = idx & 1023;
        const float4* a = (const float4*)(wf + n * WD);
        const float4* b = (const float4*)(fc2w + d * WD);
        float s = 0.f;
        #pragma unroll 5
        for (int k = 0; k < WD / 4; ++k) {
            float4 x = a[k], y = b[k];
            s += x.x * y.x + x.y * y.y + x.z * y.z + x.w * y.w;
        }
        wp[idx] = s;
    } else if (bid < 832) {                // ---- cvtW ----
        size_t base = (size_t)(bid - 320) * 4096 + (size_t)t * 16;
        #pragma unroll
        for (int j = 0; j < 4; ++j) {
            float4 v4 = *(const float4*)(fc1w + base + j * 4);
            u16x4 r = {f2bf(v4.x), f2bf(v4.y), f2bf(v4.z), f2bf(v4.w)};
            *(u16x4*)(wbf + base + j * 4) = r;
        }
    } else if (bid < 960) {                // ---- cvtA ----
        int bc = bid - 832;
        int c0 = (bc >> 2) * 64, b = bc & 3;
        for (int idx = t; idx < 64 * HW_; idx += 256) {
            int c = idx / HW_, hw = idx - c * HW_;
            tile[hw][c] = f2bf(img[((size_t)b * C_ + c0 + c) * HW_ + hw]);
        }
        __syncthreads();
        for (int q = t; q < 16 * HW_; q += 256) {
            int hw = q >> 4, c4 = (q & 15) * 4;
            u16x4 r = *(const u16x4*)&tile[hw][c4];
            *(u16x4*)(abf + ((size_t)b * HW_ + hw) * C_ + c0 + c4) = r;
        }
    } else if (bid < 1024) {               // ---- vpart ----
        int idx = bid - 960;
        int ec = idx >> 2;
        int d = (idx & 3) * 256 + t;
        float s = 0.f;
        #pragma unroll 8
        for (int e = ec * 64; e < ec * 64 + 64; ++e) s += fc4w[e] * fc3w[e * ID + d];
        vpart[ec * ID + d] = s;
    } else {                               // ---- zero lg ----
        int base = (bid - 1024) * 1024 + t * 4;
        if (base < LG_N) *(f32x4*)(lg + base) = (f32x4){0.f, 0.f, 0.f, 0.f};
    }
}

// ---- K_fused v2: fc1 tile (16p x 64d, full K=2048) + partial tanh-logits ----
// Grid (49,16) = 784 blocks (49*16 = 784 = P_, no padding). 4 waves split the
// d-tile: wave w owns d-frag j=w (one 16x16 acc frag) -> per K-step per wave:
// 1 A-read + 1 B-read + 1 MFMA. Phase 2: per-wave tanh-dot partials for all
// 16 p's over its 16 d's, accumulated to LDS red[4][80][16], merged once,
// 16 atomics per n per block. Constants (bs, sum_v) cancel in softmax.
#define LDT 72
__global__ __launch_bounds__(256) void k_fused(const unsigned short* __restrict__ Abf,
                                               const unsigned short* __restrict__ Wbf,
                                               const float* __restrict__ wp,
                                               const float* __restrict__ vpart,
                                               float* __restrict__ lg) {
    __shared__ char smem[40960];
    unsigned short (*As)[16 * LDT] = (unsigned short (*)[16 * LDT])smem;            // 2x2304B
    unsigned short (*Bs)[64 * LDT] = (unsigned short (*)[64 * LDT])(smem + 4608);   // 2x9216B
    float* wpl = (float*)smem;                    // [80][64]  20480B (phase 2)
    float* red = (float*)(smem + 20480);          // [4][80][16] 20480B (phase 2)

    int t = threadIdx.x;
    int bx = blockIdx.x, by = blockIdx.y;
    int w = t >> 6, l = t & 63;
    int lr = l & 15, lhi = l >> 4;

    // A-load: threads 0-127, row = t>>3 (16 rows), col chunk (t&7)*8
    const unsigned short* aBase = Abf + (size_t)(bx * 16 + (t >> 3)) * C_ + (t & 7) * 8;
    // B-load: all threads, row = t>>2 (64 rows), col chunk (t&3)*16
    const unsigned short* bBase = Wbf + (size_t)(by * 64 + (t >> 2)) * C_ + (t & 3) * 16;

    // v for this lane's d (= by*64 + w*16 + lr), pre-scaled by -2
    float vlane;
    {
        float s = 0.f;
        #pragma unroll
        for (int k = 0; k < 16; ++k) s += vpart[k * ID + by * 64 + w * 16 + lr];
        vlane = -2.0f * s;
    }

    short8 ra, rb0, rb1;
    f32x4 acc = (f32x4){0.f, 0.f, 0.f, 0.f};

    #define LOADR(kc) { \
        if (t < 128) ra = *(const short8*)(aBase + (kc) * 64); \
        const short8* bp = (const short8*)(bBase + (kc) * 64); \
        rb0 = bp[0]; rb1 = bp[1]; }
    #define WRITES(buf) { \
        if (t < 128) *(short8*)&As[buf][(t >> 3) * LDT + (t & 7) * 8] = ra; \
        *(short8*)&Bs[buf][(t >> 2) * LDT + (t & 3) * 16]     = rb0; \
        *(short8*)&Bs[buf][(t >> 2) * LDT + (t & 3) * 16 + 8] = rb1; }

    LOADR(0);
    WRITES(0);
    __syncthreads();

    for (int kc = 0; kc < 32; ++kc) {          // K = 2048, BK = 64
        int cur = kc & 1;
        if (kc < 31) LOADR(kc + 1);
        #pragma unroll
        for (int kk = 0; kk < 2; ++kk) {
            short8 af = *reinterpret_cast<const short8*>(
                &As[cur][lr * LDT + kk * 32 + lhi * 8]);
            short8 bf = *reinterpret_cast<const short8*>(
                &Bs[cur][(w * 16 + lr) * LDT + kk * 32 + lhi * 8]);
            acc = __builtin_amdgcn_mfma_f32_16x16x32_bf16(af, bf, acc, 0, 0, 0);
        }
        if (kc < 31) WRITES(cur ^ 1);
        __syncthreads();
    }
    #undef LOADR
    #undef WRITES

    // ---- phase 2: stage wp tile [80][64], per-wave partials, LDS merge ----
    for (int k = 0; k < 5; ++k) {              // 1280 f32x4 loads, coalesced
        int idx = t + k * 256;                 // vec4 index
        int n = idx >> 4, dl = (idx & 15) * 4;
        *(f32x4*)(wpl + idx * 4) = *(const f32x4*)(wp + (size_t)n * ID + by * 64 + dl);
    }
    __syncthreads();

    const float K2 = 2.8853900817779268f;      // 2*log2(e): exp(2x) = exp2(K2*x)
    acc *= K2;

    #pragma unroll 2
    for (int n = 0; n < NCLS; ++n) {
        float wn = wpl[n * 64 + w * 16 + lr];
        float e0 = __builtin_amdgcn_exp2f(acc[0] * wn);
        float e1 = __builtin_amdgcn_exp2f(acc[1] * wn);
        float e2 = __builtin_amdgcn_exp2f(acc[2] * wn);
        float e3 = __builtin_amdgcn_exp2f(acc[3] * wn);
        float s0 = vlane * __builtin_amdgcn_rcpf(e0 + 1.f);
        float s1 = vlane * __builtin_amdgcn_rcpf(e1 + 1.f);
        float s2 = vlane * __builtin_amdgcn_rcpf(e2 + 1.f);
        float s3 = vlane * __builtin_amdgcn_rcpf(e3 + 1.f);
        #pragma unroll
        for (int m = 1; m < 16; m <<= 1) {     // reduce over 16-lane lr group (d)
            s0 += __shfl_xor(s0, m, 64);
            s1 += __shfl_xor(s1, m, 64);
            s2 += __shfl_xor(s2, m, 64);
            s3 += __shfl_xor(s3, m, 64);
        }
        if (lr < 4) {                          // lane lr holds p-row lhi*4+lr
            float sw = (lr == 0) ? s0 : (lr == 1) ? s1 : (lr == 2) ? s2 : s3;
            red[w * 1280 + n * 16 + lhi * 4 + lr] = sw;
        }
    }
    __syncthreads();

    #pragma unroll
    for (int k = 0; k < 5; ++k) {              // merge 4 waves, 16 atomics/n
        int o = t + k * 256;                   // 0..1279 = n*16 + pl
        int n = o >> 4, pl = o & 15;
        float s = red[o] + red[1280 + o] + red[2560 + o] + red[3840 + o];
        atomicAdd(&lg[n * P_ + bx * 16 + pl], s);
    }
}

// ---- K_pool: fused softmax (over 196 positions per (b,n)) + weighted pooling ----
__global__ __launch_bounds__(256) void k_pool(const float* __restrict__ lg,
                                              const float* __restrict__ img,
                                              float* __restrict__ out) {
    __shared__ float smt[16 * HW_];
    int cb = blockIdx.x, nt = blockIdx.y, b = blockIdx.z, t = threadIdx.x;
    int n_l = t >> 4, seg = t & 15;
    int n = nt * 16 + n_l;
    float xr[13];
    float mx = -1e30f;
    #pragma unroll
    for (int j = 0; j < 13; ++j) {
        int hw = seg + j * 16;
        float x = (hw < HW_) ? lg[n * P_ + b * HW_ + hw] : -1e30f;
        xr[j] = x; mx = fmaxf(mx, x);
    }
    #pragma unroll
    for (int o = 8; o > 0; o >>= 1) mx = fmaxf(mx, __shfl_xor(mx, o, 16));
    float sum = 0.f;
    #pragma unroll
    for (int j = 0; j < 13; ++j) {
        int hw = seg + j * 16;
        float e = (hw < HW_) ? __expf(xr[j] - mx) : 0.f;
        xr[j] = e; sum += e;
    }
    #pragma unroll
    for (int o = 8; o > 0; o >>= 1) sum += __shfl_xor(sum, o, 16);
    float inv = __builtin_amdgcn_rcpf(sum);
    #pragma unroll
    for (int j = 0; j < 13; ++j) {
        int hw = seg + j * 16;
        if (hw < HW_) smt[n_l * HW_ + hw] = xr[j] * inv;
    }
    __syncthreads();

    int c = cb * 256 + t;
    const float* row = img + ((size_t)b * C_ + c) * HW_;
    float acc[16] = {};
    for (int h4 = 0; h4 < HW_ / 4; ++h4) {
        float4 iv = *(const float4*)(row + h4 * 4);
        #pragma unroll
        for (int nl = 0; nl < 16; ++nl) {
            float4 s4 = *(const float4*)&smt[nl * HW_ + h4 * 4];
            acc[nl] += iv.x * s4.x + iv.y * s4.y + iv.z * s4.z + iv.w * s4.w;
        }
    }
    #pragma unroll
    for (int nl = 0; nl < 16; ++nl)
        out[((size_t)b * NCLS + nt * 16 + nl) * C_ + c] = acc[nl];
}

extern "C" void kernel_launch(void* const* d_in, const int* in_sizes, int n_in,
                              void* d_out, int out_size, void* d_ws, size_t ws_size,
                              hipStream_t stream) {
    const float* img  = (const float*)d_in[0];
    const float* wf   = (const float*)d_in[1];
    const float* fc1w = (const float*)d_in[2];
    const float* fc2w = (const float*)d_in[3];
    const float* fc3w = (const float*)d_in[4];
    const float* fc4w = (const float*)d_in[6];
    float* out = (float*)d_out;
    float* ws  = (float*)d_ws;

    float* wp    = ws + WP_OFF;
    float* vpart = ws + VPART_OFF;
    float* lg    = ws + LG_OFF;
    unsigned short* Abf = (unsigned short*)((char*)d_ws + ABF_BYTE);
    unsigned short* Wbf = (unsigned short*)((char*)d_ws + WBF_BYTE);

    k_prep  <<<dim3(1086),    256, 0, stream>>>(img, wf, fc1w, fc2w, fc3w, fc4w,
                                                Abf, Wbf, wp, vpart, lg);
    k_fused <<<dim3(49, 16),  256, 0, stream>>>(Abf, Wbf, wp, vpart, lg);
    k_pool  <<<dim3(8, 5, 4), 256, 0, stream>>>(lg, img, out);
}

// Round 11
// 155.810 us; speedup vs baseline: 1.2512x; 1.2512x over previous
//
#include <hip/hip_runtime.h>

typedef __attribute__((ext_vector_type(8))) short short8;
typedef __attribute__((ext_vector_type(4))) float f32x4;
typedef __attribute__((ext_vector_type(4))) unsigned short u16x4;

#define B_   4
#define C_   2048
#define HW_  196
#define P_   784      // B_*HW_
#define NCLS 80
#define WD   300
#define ID   1024
#define LG_N 62720    // NCLS * P_

// workspace layout (float offsets)
#define WP_OFF    0          // word_p [80][1024]
#define VPART_OFF 81920      // vpart [16][1024]
#define LG_OFF    98304      // logits [80][784]  (n-major)
#define ABF_BYTE  644096     // Abf [784][2048] bf16
#define WBF_BYTE  3855360    // Wbf [1024][2048] bf16

__device__ __forceinline__ unsigned short f2bf(float x) {
    unsigned u = __float_as_uint(x);
    return (unsigned short)((u + 0x7FFFu + ((u >> 16) & 1u)) >> 16);  // RNE
}

// ---- K_prep: fused independent preprocessing via block-range dispatch ----
// [0,320) word_p | [320,832) cvtW | [832,960) cvtA | [960,1024) vpart | [1024,1086) zero lg
__global__ __launch_bounds__(256) void k_prep(const float* __restrict__ img,
                                              const float* __restrict__ wf,
                                              const float* __restrict__ fc1w,
                                              const float* __restrict__ fc2w,
                                              const float* __restrict__ fc3w,
                                              const float* __restrict__ fc4w,
                                              unsigned short* __restrict__ abf,
                                              unsigned short* __restrict__ wbf,
                                              float* __restrict__ wp,
                                              float* __restrict__ vpart,
                                              float* __restrict__ lg) {
    __shared__ unsigned short tile[HW_][68];
    int bid = blockIdx.x, t = threadIdx.x;
    if (bid < 320) {                       // ---- word_p ----
        int idx = bid * 256 + t;
        int n = idx >> 10, d = idx & 1023;
        const float4* a = (const float4*)(wf + n * WD);
        const float4* b = (const float4*)(fc2w + d * WD);
        float s = 0.f;
        #pragma unroll 5
        for (int k = 0; k < WD / 4; ++k) {
            float4 x = a[k], y = b[k];
            s += x.x * y.x + x.y * y.y + x.z * y.z + x.w * y.w;
        }
        wp[idx] = s;
    } else if (bid < 832) {                // ---- cvtW ----
        size_t base = (size_t)(bid - 320) * 4096 + (size_t)t * 16;
        #pragma unroll
        for (int j = 0; j < 4; ++j) {
            float4 v4 = *(const float4*)(fc1w + base + j * 4);
            u16x4 r = {f2bf(v4.x), f2bf(v4.y), f2bf(v4.z), f2bf(v4.w)};
            *(u16x4*)(wbf + base + j * 4) = r;
        }
    } else if (bid < 960) {                // ---- cvtA ----
        int bc = bid - 832;
        int c0 = (bc >> 2) * 64, b = bc & 3;
        for (int idx = t; idx < 64 * HW_; idx += 256) {
            int c = idx / HW_, hw = idx - c * HW_;
            tile[hw][c] = f2bf(img[((size_t)b * C_ + c0 + c) * HW_ + hw]);
        }
        __syncthreads();
        for (int q = t; q < 16 * HW_; q += 256) {
            int hw = q >> 4, c4 = (q & 15) * 4;
            u16x4 r = *(const u16x4*)&tile[hw][c4];
            *(u16x4*)(abf + ((size_t)b * HW_ + hw) * C_ + c0 + c4) = r;
        }
    } else if (bid < 1024) {               // ---- vpart ----
        int idx = bid - 960;
        int ec = idx >> 2;
        int d = (idx & 3) * 256 + t;
        float s = 0.f;
        #pragma unroll 8
        for (int e = ec * 64; e < ec * 64 + 64; ++e) s += fc4w[e] * fc3w[e * ID + d];
        vpart[ec * ID + d] = s;
    } else {                               // ---- zero lg ----
        int base = (bid - 1024) * 1024 + t * 4;
        if (base < LG_N) *(f32x4*)(lg + base) = (f32x4){0.f, 0.f, 0.f, 0.f};
    }
}

// ---- K_fused v3: fc1 tile (16p x 64d) + tanh-logits, SWAPPED-MFMA layout ----
// Grid (49,16) = 784 blocks. 4 waves split the 64-d tile (wave w: d-slice w*16).
// mfma(af=Wbf-frag, bf=Abf-frag) -> acc transposed: lane (lr,lhi) holds
// imgp[p = bx*16+lr][d = by*64+w*16+lhi*4+i] — the logits d-sum is LANE-LOCAL
// (4 d's per lane, no shuffles), wave 16-d slice closes with 2 butterflies.
// Constants (bs, sum_v) cancel in softmax and are dropped.
#define LDT 72
__global__ __launch_bounds__(256) void k_fused(const unsigned short* __restrict__ Abf,
                                               const unsigned short* __restrict__ Wbf,
                                               const float* __restrict__ wp,
                                               const float* __restrict__ vpart,
                                               float* __restrict__ lg) {
    __shared__ char smem[40960];
    unsigned short (*As)[16 * LDT] = (unsigned short (*)[16 * LDT])smem;            // 2x2304B
    unsigned short (*Bs)[64 * LDT] = (unsigned short (*)[64 * LDT])(smem + 4608);   // 2x9216B
    float* wpl = (float*)smem;                    // [80][64]  20480B (phase 2)
    float* red = (float*)(smem + 20480);          // [4][80][16] 20480B (phase 2)

    int t = threadIdx.x;
    int bx = blockIdx.x, by = blockIdx.y;
    int w = t >> 6, l = t & 63;
    int lr = l & 15, lhi = l >> 4;

    // A-load: threads 0-127, row = t>>3 (16 rows), col chunk (t&7)*8
    const unsigned short* aBase = Abf + (size_t)(bx * 16 + (t >> 3)) * C_ + (t & 7) * 8;
    // B-load: all threads, row = t>>2 (64 rows), col chunk (t&3)*16
    const unsigned short* bBase = Wbf + (size_t)(by * 64 + (t >> 2)) * C_ + (t & 3) * 16;

    // v for this lane's 4 d's (= by*64 + w*16 + lhi*4 + i), pre-scaled by -2
    f32x4 vj = (f32x4){0.f, 0.f, 0.f, 0.f};
    #pragma unroll
    for (int k = 0; k < 16; ++k)
        vj += *(const f32x4*)(vpart + k * ID + by * 64 + w * 16 + lhi * 4);
    vj *= -2.0f;

    short8 ra, rb0, rb1;
    f32x4 acc = (f32x4){0.f, 0.f, 0.f, 0.f};

    #define LOADR(kc) { \
        if (t < 128) ra = *(const short8*)(aBase + (kc) * 64); \
        const short8* bp = (const short8*)(bBase + (kc) * 64); \
        rb0 = bp[0]; rb1 = bp[1]; }
    #define WRITES(buf) { \
        if (t < 128) *(short8*)&As[buf][(t >> 3) * LDT + (t & 7) * 8] = ra; \
        *(short8*)&Bs[buf][(t >> 2) * LDT + (t & 3) * 16]     = rb0; \
        *(short8*)&Bs[buf][(t >> 2) * LDT + (t & 3) * 16 + 8] = rb1; }

    LOADR(0);
    WRITES(0);
    __syncthreads();

    for (int kc = 0; kc < 32; ++kc) {          // K = 2048, BK = 64
        int cur = kc & 1;
        if (kc < 31) LOADR(kc + 1);
        #pragma unroll
        for (int kk = 0; kk < 2; ++kk) {
            short8 df = *reinterpret_cast<const short8*>(      // d-side (M operand)
                &Bs[cur][(w * 16 + lr) * LDT + kk * 32 + lhi * 8]);
            short8 pf = *reinterpret_cast<const short8*>(      // p-side (N operand)
                &As[cur][lr * LDT + kk * 32 + lhi * 8]);
            acc = __builtin_amdgcn_mfma_f32_16x16x32_bf16(df, pf, acc, 0, 0, 0);
        }
        if (kc < 31) WRITES(cur ^ 1);
        __syncthreads();
    }
    #undef LOADR
    #undef WRITES

    // ---- phase 2: stage wp tile [80][64], lane-local tanh-dot, 2-shfl close ----
    for (int k = 0; k < 5; ++k) {              // 1280 f32x4 loads, coalesced
        int idx = t + k * 256;                 // vec4 index
        int n = idx >> 4, dl = (idx & 15) * 4;
        *(f32x4*)(wpl + idx * 4) = *(const f32x4*)(wp + (size_t)n * ID + by * 64 + dl);
    }
    __syncthreads();

    const float K2 = 2.8853900817779268f;      // 2*log2(e): exp(2x) = exp2(K2*x)
    acc *= K2;

    #pragma unroll 2
    for (int n = 0; n < NCLS; ++n) {
        f32x4 wn = *(const f32x4*)(wpl + n * 64 + w * 16 + lhi * 4);  // b128 broadcast
        float e0 = __builtin_amdgcn_exp2f(acc[0] * wn[0]);
        float e1 = __builtin_amdgcn_exp2f(acc[1] * wn[1]);
        float e2 = __builtin_amdgcn_exp2f(acc[2] * wn[2]);
        float e3 = __builtin_amdgcn_exp2f(acc[3] * wn[3]);
        float s = vj[0] * __builtin_amdgcn_rcpf(e0 + 1.f)
                + vj[1] * __builtin_amdgcn_rcpf(e1 + 1.f)
                + vj[2] * __builtin_amdgcn_rcpf(e2 + 1.f)
                + vj[3] * __builtin_amdgcn_rcpf(e3 + 1.f);
        s += __shfl_xor(s, 16, 64);            // close the wave's 16-d slice
        s += __shfl_xor(s, 32, 64);
        if (l < 16) red[w * 1280 + n * 16 + l] = s;   // p = bx*16 + l
    }
    __syncthreads();

    #pragma unroll
    for (int k = 0; k < 5; ++k) {              // merge 4 waves, 16 atomics/n
        int o = t + k * 256;                   // 0..1279 = n*16 + pl
        int n = o >> 4, pl = o & 15;
        float s = red[o] + red[1280 + o] + red[2560 + o] + red[3840 + o];
        atomicAdd(&lg[n * P_ + bx * 16 + pl], s);
    }
}

// ---- K_pool: fused softmax (over 196 positions per (b,n)) + weighted pooling ----
__global__ __launch_bounds__(256) void k_pool(const float* __restrict__ lg,
                                              const float* __restrict__ img,
                                              float* __restrict__ out) {
    __shared__ float smt[16 * HW_];
    int cb = blockIdx.x, nt = blockIdx.y, b = blockIdx.z, t = threadIdx.x;
    int n_l = t >> 4, seg = t & 15;
    int n = nt * 16 + n_l;
    float xr[13];
    float mx = -1e30f;
    #pragma unroll
    for (int j = 0; j < 13; ++j) {
        int hw = seg + j * 16;
        float x = (hw < HW_) ? lg[n * P_ + b * HW_ + hw] : -1e30f;
        xr[j] = x; mx = fmaxf(mx, x);
    }
    #pragma unroll
    for (int o = 8; o > 0; o >>= 1) mx = fmaxf(mx, __shfl_xor(mx, o, 16));
    float sum = 0.f;
    #pragma unroll
    for (int j = 0; j < 13; ++j) {
        int hw = seg + j * 16;
        float e = (hw < HW_) ? __expf(xr[j] - mx) : 0.f;
        xr[j] = e; sum += e;
    }
    #pragma unroll
    for (int o = 8; o > 0; o >>= 1) sum += __shfl_xor(sum, o, 16);
    float inv = __builtin_amdgcn_rcpf(sum);
    #pragma unroll
    for (int j = 0; j < 13; ++j) {
        int hw = seg + j * 16;
        if (hw < HW_) smt[n_l * HW_ + hw] = xr[j] * inv;
    }
    __syncthreads();

    int c = cb * 256 + t;
    const float* row = img + ((size_t)b * C_ + c) * HW_;
    float acc[16] = {};
    for (int h4 = 0; h4 < HW_ / 4; ++h4) {
        float4 iv = *(const float4*)(row + h4 * 4);
        #pragma unroll
        for (int nl = 0; nl < 16; ++nl) {
            float4 s4 = *(const float4*)&smt[nl * HW_ + h4 * 4];
            acc[nl] += iv.x * s4.x + iv.y * s4.y + iv.z * s4.z + iv.w * s4.w;
        }
    }
    #pragma unroll
    for (int nl = 0; nl < 16; ++nl)
        out[((size_t)b * NCLS + nt * 16 + nl) * C_ + c] = acc[nl];
}

extern "C" void kernel_launch(void* const* d_in, const int* in_sizes, int n_in,
                              void* d_out, int out_size, void* d_ws, size_t ws_size,
                              hipStream_t stream) {
    const float* img  = (const float*)d_in[0];
    const float* wf   = (const float*)d_in[1];
    const float* fc1w = (const float*)d_in[2];
    const float* fc2w = (const float*)d_in[3];
    const float* fc3w = (const float*)d_in[4];
    const float* fc4w = (const float*)d_in[6];
    float* out = (float*)d_out;
    float* ws  = (float*)d_ws;

    float* wp    = ws + WP_OFF;
    float* vpart = ws + VPART_OFF;
    float* lg    = ws + LG_OFF;
    unsigned short* Abf = (unsigned short*)((char*)d_ws + ABF_BYTE);
    unsigned short* Wbf = (unsigned short*)((char*)d_ws + WBF_BYTE);

    k_prep  <<<dim3(1086),    256, 0, stream>>>(img, wf, fc1w, fc2w, fc3w, fc4w,
                                                Abf, Wbf, wp, vpart, lg);
    k_fused <<<dim3(49, 16),  256, 0, stream>>>(Abf, Wbf, wp, vpart, lg);
    k_pool  <<<dim3(8, 5, 4), 256, 0, stream>>>(lg, img, out);
}